// Round 4
// baseline (864.472 us; speedup 1.0000x reference)
//
#include <hip/hip_runtime.h>
#include <cstdint>
#include <cstddef>

typedef int v4i  __attribute__((ext_vector_type(4)));
typedef int v16i __attribute__((ext_vector_type(16)));

// ---------------------------------------------------------------------------
// async global->LDS 16B copy. LDS dest is wave-uniform base + lane*16.
// ---------------------------------------------------------------------------
__device__ __forceinline__ void load_lds16(const void* g, void* l) {
    __builtin_amdgcn_global_load_lds(
        (const __attribute__((address_space(1))) void*)g,
        (__attribute__((address_space(3))) void*)l,
        16, 0, 0);
}

// ---------------------------------------------------------------------------
// Kernel 1: sum of |W| (double accumulation; a ternary rounding-boundary flip
// is worth ~0.09 absmax vs threshold 0.105, so keep the mean exact)
// ---------------------------------------------------------------------------
__global__ void wabs_sum_kernel(const float4* __restrict__ w4,
                                double* __restrict__ acc, int n4) {
    double s = 0.0;
    for (int i = blockIdx.x * blockDim.x + threadIdx.x; i < n4;
         i += gridDim.x * blockDim.x) {
        float4 v = w4[i];
        s += (double)fabsf(v.x) + (double)fabsf(v.y) +
             (double)fabsf(v.z) + (double)fabsf(v.w);
    }
    for (int o = 32; o > 0; o >>= 1) s += __shfl_down(s, o);
    __shared__ double sb[4];
    const int wid = threadIdx.x >> 6, lane = threadIdx.x & 63;
    if (lane == 0) sb[wid] = s;
    __syncthreads();
    if (threadIdx.x == 0) atomicAdd(acc, sb[0] + sb[1] + sb[2] + sb[3]);
}

__device__ __forceinline__ float sw_from_sum(const double* sump, int n) {
    float mean = (float)(*sump / (double)n);
    return 1.0f / fmaxf(mean, 1e-5f);   // sw = 1/max(mean|W|, Q_EPS)
}

// ---------------------------------------------------------------------------
// Kernel 2: ternary weight quantization -> int8 {-1,0,1}, row-major [O,K]
// ---------------------------------------------------------------------------
__global__ void wquant_kernel(const float4* __restrict__ w4,
                              const double* __restrict__ sump,
                              char4* __restrict__ wq4, int n4, int n) {
    const float s = sw_from_sum(sump, n);
    int i = blockIdx.x * blockDim.x + threadIdx.x;
    if (i >= n4) return;
    float4 v = w4[i];
    char4 q;
    q.x = (signed char)(int)fmaxf(-1.f, fminf(1.f, rintf(v.x * s)));
    q.y = (signed char)(int)fmaxf(-1.f, fminf(1.f, rintf(v.y * s)));
    q.z = (signed char)(int)fmaxf(-1.f, fminf(1.f, rintf(v.z * s)));
    q.w = (signed char)(int)fmaxf(-1.f, fminf(1.f, rintf(v.w * s)));
    wq4[i] = q;
}

// ---------------------------------------------------------------------------
// Kernel 3: fused RMSNorm + per-token int8 act quant.
// One block per token row (D=4096, 256 thr * 16 elems, kept in registers).
// Also writes rscale[m] = 1/(sx*sw) for the GEMM epilogue.
// ---------------------------------------------------------------------------
__global__ __launch_bounds__(256) void act_quant_kernel(
    const float* __restrict__ x, const float* __restrict__ nw,
    const double* __restrict__ sump, int wcount,
    signed char* __restrict__ hq, float* __restrict__ rscale, int D) {
    const int m = blockIdx.x;
    const int t = threadIdx.x;
    const float4* xr  = (const float4*)(x + (size_t)m * D);
    const float4* nw4 = (const float4*)nw;

    float4 v[4];
    float ss = 0.f;
#pragma unroll
    for (int i = 0; i < 4; ++i) {
        v[i] = xr[t + 256 * i];
        ss += v[i].x * v[i].x + v[i].y * v[i].y +
              v[i].z * v[i].z + v[i].w * v[i].w;
    }
    for (int o = 32; o > 0; o >>= 1) ss += __shfl_down(ss, o);
    __shared__ float sb[4];
    const int wid = t >> 6, lane = t & 63;
    if (lane == 0) sb[wid] = ss;
    __syncthreads();
    const float var  = (sb[0] + sb[1] + sb[2] + sb[3]) / (float)D;
    const float rstd = (float)(1.0 / sqrt((double)var + 1e-5));
    __syncthreads();   // sb re-used below

    float mx = 0.f;
#pragma unroll
    for (int i = 0; i < 4; ++i) {
        float4 g = nw4[t + 256 * i];
        v[i].x = v[i].x * rstd * g.x;
        v[i].y = v[i].y * rstd * g.y;
        v[i].z = v[i].z * rstd * g.z;
        v[i].w = v[i].w * rstd * g.w;
        mx = fmaxf(mx, fmaxf(fmaxf(fabsf(v[i].x), fabsf(v[i].y)),
                             fmaxf(fabsf(v[i].z), fabsf(v[i].w))));
    }
    for (int o = 32; o > 0; o >>= 1) mx = fmaxf(mx, __shfl_down(mx, o));
    if (lane == 0) sb[wid] = mx;
    __syncthreads();
    const float mxa   = fmaxf(fmaxf(sb[0], sb[1]), fmaxf(sb[2], sb[3]));
    const float scale = 127.0f / fmaxf(mxa, 1e-5f);

    char4* hq4 = (char4*)(hq + (size_t)m * D);
#pragma unroll
    for (int i = 0; i < 4; ++i) {
        char4 q;
        q.x = (signed char)(int)fmaxf(-128.f, fminf(127.f, rintf(v[i].x * scale)));
        q.y = (signed char)(int)fmaxf(-128.f, fminf(127.f, rintf(v[i].y * scale)));
        q.z = (signed char)(int)fmaxf(-128.f, fminf(127.f, rintf(v[i].z * scale)));
        q.w = (signed char)(int)fmaxf(-128.f, fminf(127.f, rintf(v[i].w * scale)));
        hq4[t + 256 * i] = q;
    }
    if (t == 0) {
        const float sw = sw_from_sum(sump, wcount);
        rscale[m] = 1.0f / (scale * sw);
    }
}

// ---------------------------------------------------------------------------
// Kernel 4: int8 GEMM  C[m,n] = sum_k A[m,k]*B[n,k]  (both K-contiguous, NT)
//
// Pipelined 256x256 tile, BK=64, 8 waves (2M x 4N), each wave owns 128x64.
// 4-deep LDS K-tile rotation (128 KiB), global_load_lds width-16 staging
// issued 3 tiles ahead, ONE barrier per K-tile with a COUNTED vmcnt.
//
// HARDENING (round 4): the per-tile barrier is a single inline-asm block
// "s_waitcnt vmcnt(N) ; s_barrier". Round-3's container compiled the
// __builtin_amdgcn_s_barrier() version with +8 VGPR and +190us of pure stall
// (MfmaUtil 57.6->29.0 at constant MFMA issue-time), consistent with that
// compiler attaching a vmcnt(0) drain to the builtin barrier (the documented
// __syncthreads legalizer behavior). A raw asm s_barrier is opaque to the
// legalizer, so no drain can be attached; the explicit counted vmcnt ladder
// (8 in steady state, 8->4->0 on the last 3 tiles) provides the only wait
// needed for correctness: all cross-wave LDS writes are global_load_lds ops
// retired by each wave's own vmcnt before it reaches the barrier.
//
// LDS swizzle (quarter-wave bank-balanced): 16B k-chunk c of row r stored at
// slot c ^ ((r>>2)&3); slot bits are independent of the row-parity bank bit,
// so every 16-lane quarter of a ds_read_b128 covers all 8 base positions
// with 2 lanes each = the b128 conflict floor (measured: 7.55e7 -> 2.1e6
// conflicts vs the round-1 c^(r&3) variant). Staging pre-swizzles the GLOBAL
// source address ((lane&3)^((lane>>4)&3)); LDS dest stays linear.
//
// Per tile/wave: {4 stage issues | 12 ds_read_b128 | setprio(1) | 16 MFMA |
// setprio(0) | vmcnt(8)+s_barrier}.
// Assumes M%256==0, N%256==0, K%64==0, K/64 >= 4 (holds: 16384/4096/4096).
// ---------------------------------------------------------------------------
constexpr int BM = 256, BN = 256, BK = 64;

template<int VM>
__device__ __forceinline__ void wait_barrier() {
    if (VM == 8)
        asm volatile("s_waitcnt vmcnt(8)\n\ts_barrier" ::: "memory");
    else if (VM == 4)
        asm volatile("s_waitcnt vmcnt(4)\n\ts_barrier" ::: "memory");
    else if (VM == 0)
        asm volatile("s_waitcnt vmcnt(0)\n\ts_barrier" ::: "memory");
    else
        asm volatile("s_barrier" ::: "memory");
}

template<bool STAGE, int VM>
__device__ __forceinline__ void gemm_tile(
    int t, signed char (*As)[BM * BK], signed char (*Bs)[BN * BK],
    const signed char* aSrc, const signed char* bSrc, int K, int ldsOff,
    int wm, int wn, int r32, int h, v16i (&acc)[4][2])
{
    const int buf = t & 3;

    if (STAGE) {   // issue tile t+3 into buf (t+3)&3 = (t-1)&3 (dead: its
                   // readers all passed the end-of-(t-1) barrier)
        const size_t kt = (size_t)(t + 3) * BK;
        signed char* da = &As[(t + 3) & 3][ldsOff];
        signed char* db = &Bs[(t + 3) & 3][ldsOff];
        load_lds16(aSrc + kt, da);
        load_lds16(aSrc + kt + (size_t)16 * K, da + 1024);
        load_lds16(bSrc + kt, db);
        load_lds16(bSrc + kt + (size_t)16 * K, db + 1024);
    }

    // fragment reads: A rows wm*128+mf*32+r32, B rows wn*64+nf*32+r32;
    // global k-chunk g = 2ks+h at slot g ^ ((row>>2)&3); (row>>2)&3 ==
    // (r32>>2)&3 since all row bases are multiples of 32.
    const int rs = (r32 >> 2) & 3;
    v4i af[2][4], bf[2][2];
#pragma unroll
    for (int ks = 0; ks < 2; ++ks) {
        const int slot = ((2 * ks + h) ^ rs) * 16;
#pragma unroll
        for (int mf = 0; mf < 4; ++mf)
            af[ks][mf] = *(const v4i*)&As[buf][(wm * 128 + mf * 32 + r32) * BK + slot];
#pragma unroll
        for (int nf = 0; nf < 2; ++nf)
            bf[ks][nf] = *(const v4i*)&Bs[buf][(wn * 64 + nf * 32 + r32) * BK + slot];
    }

    __builtin_amdgcn_s_setprio(1);
#pragma unroll
    for (int ks = 0; ks < 2; ++ks)     // ks outer: 8 independent chains first
#pragma unroll
        for (int mf = 0; mf < 4; ++mf)
#pragma unroll
            for (int nf = 0; nf < 2; ++nf)
                acc[mf][nf] = __builtin_amdgcn_mfma_i32_32x32x32_i8(
                    af[ks][mf], bf[ks][nf], acc[mf][nf], 0, 0, 0);
    __builtin_amdgcn_s_setprio(0);

    // counted wait fused with the barrier: keep tiles t+2,t+3 (8 loads) in
    // flight; the oldest group (tile t+1, read next) is guaranteed landed.
    wait_barrier<VM>();
}

__global__ __launch_bounds__(512, 2) void gemm_i8_kernel(
    const signed char* __restrict__ A, const signed char* __restrict__ B,
    const float* __restrict__ rscale, float* __restrict__ out,
    int M, int N, int K) {
    __shared__ signed char As[4][BM * BK];   // 64 KiB
    __shared__ signed char Bs[4][BN * BK];   // 64 KiB

    const int tid  = threadIdx.x;
    const int wave = tid >> 6;
    const int lane = tid & 63;
    const int wm   = wave >> 2;   // 0..1 : 128-row band
    const int wn   = wave & 3;    // 0..3 : 64-col band
    const int r32  = lane & 31;
    const int h    = lane >> 5;

    // XCD-aware bijective block swizzle (nwg % 8 == 0 here: 16*64 = 1024)
    const int nwg = gridDim.x * gridDim.y;
    int lin = blockIdx.y * gridDim.x + blockIdx.x;
    lin = (lin & 7) * (nwg >> 3) + (lin >> 3);
    const int m0 = (lin / (int)gridDim.x) * BM;
    const int n0 = (lin % (int)gridDim.x) * BN;

    // staging: tile = 16 chunks of 1024B (16 rows x 64B) per operand; wave w
    // owns rows [32w,32w+32) = 2 chunks each of A and B. lane L -> LDS off
    // L*16 = row L>>2, slot L&3; content = global k-chunk (L&3)^((L>>4)&3)
    // (chunks are 16-row aligned so (row>>2)&3 == (L>>4)&3).
    const int lrow = lane >> 2;
    const int lswz = ((lane & 3) ^ ((lane >> 4) & 3)) * 16;
    const signed char* aSrc = A + (size_t)(m0 + wave * 32 + lrow) * K + lswz;
    const signed char* bSrc = B + (size_t)(n0 + wave * 32 + lrow) * K + lswz;
    const int ldsOff = wave * 2048;

    v16i acc[4][2] = {};

    // prologue: stage tiles 0..2 into bufs 0..2 (contiguous 4-load groups)
#pragma unroll
    for (int p = 0; p < 3; ++p) {
        const size_t kt = (size_t)p * BK;
        signed char* da = &As[p][ldsOff];
        signed char* db = &Bs[p][ldsOff];
        load_lds16(aSrc + kt, da);
        load_lds16(aSrc + kt + (size_t)16 * K, da + 1024);
        load_lds16(bSrc + kt, db);
        load_lds16(bSrc + kt + (size_t)16 * K, db + 1024);
    }
    wait_barrier<8>();   // tile 0 landed; tiles 1,2 still in flight

    const int NT = K >> 6;
    int t = 0;
    for (; t < NT - 3; ++t)
        gemm_tile<true, 8>(t, As, Bs, aSrc, bSrc, K, ldsOff, wm, wn, r32, h, acc);
    gemm_tile<false, 4>(NT - 3, As, Bs, aSrc, bSrc, K, ldsOff, wm, wn, r32, h, acc);
    gemm_tile<false, 0>(NT - 2, As, Bs, aSrc, bSrc, K, ldsOff, wm, wn, r32, h, acc);
    gemm_tile<false, -1>(NT - 1, As, Bs, aSrc, bSrc, K, ldsOff, wm, wn, r32, h, acc);

    // epilogue: 32x32 C/D layout: col = lane&31, row = (reg&3)+8*(reg>>2)+4*h
#pragma unroll
    for (int mf = 0; mf < 4; ++mf) {
#pragma unroll
        for (int reg = 0; reg < 16; ++reg) {
            const int m = m0 + wm * 128 + mf * 32 + (reg & 3) + 8 * (reg >> 2) + 4 * h;
            const float rs = rscale[m];
            const size_t rowoff = (size_t)m * N + n0 + wn * 64 + r32;
#pragma unroll
            for (int nf = 0; nf < 2; ++nf)
                out[rowoff + nf * 32] = (float)acc[mf][nf][reg] * rs;
        }
    }
}

// ---------------------------------------------------------------------------
extern "C" void kernel_launch(void* const* d_in, const int* in_sizes, int n_in,
                              void* d_out, int out_size, void* d_ws, size_t ws_size,
                              hipStream_t stream) {
    const float* x  = (const float*)d_in[0];   // [B,S,D] fp32
    const float* nw = (const float*)d_in[1];   // [D]
    const float* w  = (const float*)d_in[2];   // [O,D]
    const int D = in_sizes[1];
    const int M = in_sizes[0] / D;             // B*S tokens
    const int O = in_sizes[2] / D;
    const int WN = O * D;                      // weight element count

    char* ws = (char*)d_ws;
    double* d_sum    = (double*)(ws + 0);
    float*  d_rscale = (float*)(ws + 128);
    size_t off = 128 + (size_t)M * sizeof(float);
    off = (off + 255) & ~(size_t)255;
    signed char* d_wq = (signed char*)(ws + off);
    off += (size_t)WN;
    off = (off + 255) & ~(size_t)255;
    signed char* d_hq = (signed char*)(ws + off);

    hipMemsetAsync(d_sum, 0, sizeof(double), stream);

    wabs_sum_kernel<<<4096, 256, 0, stream>>>((const float4*)w, d_sum, WN / 4);

    wquant_kernel<<<(WN / 4 + 255) / 256, 256, 0, stream>>>(
        (const float4*)w, d_sum, (char4*)d_wq, WN / 4, WN);

    act_quant_kernel<<<M, 256, 0, stream>>>(x, nw, d_sum, WN, d_hq, d_rscale, D);

    dim3 grid(O / 256, M / 256);
    gemm_i8_kernel<<<grid, 512, 0, stream>>>(d_hq, d_wq, d_rscale,
                                             (float*)d_out, M, O, D);
}

// Round 5
// 791.967 us; speedup vs baseline: 1.0916x; 1.0916x over previous
//
#include <hip/hip_runtime.h>
#include <cstdint>
#include <cstddef>

typedef int v4i  __attribute__((ext_vector_type(4)));
typedef int v16i __attribute__((ext_vector_type(16)));

// ---------------------------------------------------------------------------
// async global->LDS 16B copy. LDS dest is wave-uniform base + lane*16.
// ---------------------------------------------------------------------------
__device__ __forceinline__ void load_lds16(const void* g, void* l) {
    __builtin_amdgcn_global_load_lds(
        (const __attribute__((address_space(1))) void*)g,
        (__attribute__((address_space(3))) void*)l,
        16, 0, 0);
}

// 32-bit LDS byte address of a __shared__ object (ptrtoint of AS3 pointer).
__device__ __forceinline__ uint32_t lds_addr(const void* p) {
    return (uint32_t)(uintptr_t)(const __attribute__((address_space(3))) void*)p;
}

// Inline-asm ds_read_b128: opaque to the waitcnt-insertion pass, so the
// compiler cannot attach a conservative "s_waitcnt vmcnt(0)" (drain of
// outstanding global_load_lds) in front of it. Completion is claimed
// manually via s_waitcnt lgkmcnt(0) + sched_barrier(0) before the MFMAs.
__device__ __forceinline__ v4i ds_read_b128_asm(uint32_t addr) {
    v4i r;
    asm volatile("ds_read_b128 %0, %1" : "=v"(r) : "v"(addr));
    return r;
}

// ---------------------------------------------------------------------------
// Kernel 1: sum of |W| (double accumulation; a ternary rounding-boundary flip
// is worth ~0.09 absmax vs threshold 0.105, so keep the mean exact)
// ---------------------------------------------------------------------------
__global__ void wabs_sum_kernel(const float4* __restrict__ w4,
                                double* __restrict__ acc, int n4) {
    double s = 0.0;
    for (int i = blockIdx.x * blockDim.x + threadIdx.x; i < n4;
         i += gridDim.x * blockDim.x) {
        float4 v = w4[i];
        s += (double)fabsf(v.x) + (double)fabsf(v.y) +
             (double)fabsf(v.z) + (double)fabsf(v.w);
    }
    for (int o = 32; o > 0; o >>= 1) s += __shfl_down(s, o);
    __shared__ double sb[4];
    const int wid = threadIdx.x >> 6, lane = threadIdx.x & 63;
    if (lane == 0) sb[wid] = s;
    __syncthreads();
    if (threadIdx.x == 0) atomicAdd(acc, sb[0] + sb[1] + sb[2] + sb[3]);
}

__device__ __forceinline__ float sw_from_sum(const double* sump, int n) {
    float mean = (float)(*sump / (double)n);
    return 1.0f / fmaxf(mean, 1e-5f);   // sw = 1/max(mean|W|, Q_EPS)
}

// ---------------------------------------------------------------------------
// Kernel 2: ternary weight quantization -> int8 {-1,0,1}, row-major [O,K]
// ---------------------------------------------------------------------------
__global__ void wquant_kernel(const float4* __restrict__ w4,
                              const double* __restrict__ sump,
                              char4* __restrict__ wq4, int n4, int n) {
    const float s = sw_from_sum(sump, n);
    int i = blockIdx.x * blockDim.x + threadIdx.x;
    if (i >= n4) return;
    float4 v = w4[i];
    char4 q;
    q.x = (signed char)(int)fmaxf(-1.f, fminf(1.f, rintf(v.x * s)));
    q.y = (signed char)(int)fmaxf(-1.f, fminf(1.f, rintf(v.y * s)));
    q.z = (signed char)(int)fmaxf(-1.f, fminf(1.f, rintf(v.z * s)));
    q.w = (signed char)(int)fmaxf(-1.f, fminf(1.f, rintf(v.w * s)));
    wq4[i] = q;
}

// ---------------------------------------------------------------------------
// Kernel 3: fused RMSNorm + per-token int8 act quant.
// One block per token row (D=4096, 256 thr * 16 elems, kept in registers).
// Also writes rscale[m] = 1/(sx*sw) for the GEMM epilogue.
// ---------------------------------------------------------------------------
__global__ __launch_bounds__(256) void act_quant_kernel(
    const float* __restrict__ x, const float* __restrict__ nw,
    const double* __restrict__ sump, int wcount,
    signed char* __restrict__ hq, float* __restrict__ rscale, int D) {
    const int m = blockIdx.x;
    const int t = threadIdx.x;
    const float4* xr  = (const float4*)(x + (size_t)m * D);
    const float4* nw4 = (const float4*)nw;

    float4 v[4];
    float ss = 0.f;
#pragma unroll
    for (int i = 0; i < 4; ++i) {
        v[i] = xr[t + 256 * i];
        ss += v[i].x * v[i].x + v[i].y * v[i].y +
              v[i].z * v[i].z + v[i].w * v[i].w;
    }
    for (int o = 32; o > 0; o >>= 1) ss += __shfl_down(ss, o);
    __shared__ float sb[4];
    const int wid = t >> 6, lane = t & 63;
    if (lane == 0) sb[wid] = ss;
    __syncthreads();
    const float var  = (sb[0] + sb[1] + sb[2] + sb[3]) / (float)D;
    const float rstd = (float)(1.0 / sqrt((double)var + 1e-5));
    __syncthreads();   // sb re-used below

    float mx = 0.f;
#pragma unroll
    for (int i = 0; i < 4; ++i) {
        float4 g = nw4[t + 256 * i];
        v[i].x = v[i].x * rstd * g.x;
        v[i].y = v[i].y * rstd * g.y;
        v[i].z = v[i].z * rstd * g.z;
        v[i].w = v[i].w * rstd * g.w;
        mx = fmaxf(mx, fmaxf(fmaxf(fabsf(v[i].x), fabsf(v[i].y)),
                             fmaxf(fabsf(v[i].z), fabsf(v[i].w))));
    }
    for (int o = 32; o > 0; o >>= 1) mx = fmaxf(mx, __shfl_down(mx, o));
    if (lane == 0) sb[wid] = mx;
    __syncthreads();
    const float mxa   = fmaxf(fmaxf(sb[0], sb[1]), fmaxf(sb[2], sb[3]));
    const float scale = 127.0f / fmaxf(mxa, 1e-5f);

    char4* hq4 = (char4*)(hq + (size_t)m * D);
#pragma unroll
    for (int i = 0; i < 4; ++i) {
        char4 q;
        q.x = (signed char)(int)fmaxf(-128.f, fminf(127.f, rintf(v[i].x * scale)));
        q.y = (signed char)(int)fmaxf(-128.f, fminf(127.f, rintf(v[i].y * scale)));
        q.z = (signed char)(int)fmaxf(-128.f, fminf(127.f, rintf(v[i].z * scale)));
        q.w = (signed char)(int)fmaxf(-128.f, fminf(127.f, rintf(v[i].w * scale)));
        hq4[t + 256 * i] = q;
    }
    if (t == 0) {
        const float sw = sw_from_sum(sump, wcount);
        rscale[m] = 1.0f / (scale * sw);
    }
}

// ---------------------------------------------------------------------------
// Kernel 4: int8 GEMM  C[m,n] = sum_k A[m,k]*B[n,k]  (both K-contiguous, NT)
//
// Pipelined 256x256 tile, BK=64, 8 waves (2M x 4N), each wave owns 128x64.
// 4-deep LDS K-tile rotation (128 KiB), global_load_lds width-16 staging
// issued 3 tiles ahead, ONE barrier per K-tile with a COUNTED vmcnt
// ("s_waitcnt vmcnt(8); s_barrier" fused asm; ladder 8->4->0 at the tail).
//
// ROUND-5 FIX: fragment reads are inline-asm ds_read_b128 (opaque to the
// waitcnt pass). Rounds 3/4 measured ~1800 stall cycles/tile at constant
// MFMA issue-time (MfmaUtil 57.6 -> 29) on a container whose compiler
// (VGPR 92 -> 100 on identical source) inserts a conservative
// "s_waitcnt vmcnt(0)" before DS-class instructions while global_load_lds
// ops are outstanding (runtime buffer index -> unprovable non-alias): each
// tile then drains its OWN just-issued staging, serializing the pipeline.
// Asm ds_reads carry no DS opcode for the pass to guard; the manual
// lgkmcnt(0) + sched_barrier(0) (rule: compiler hoists register-only MFMAs
// past asm waitcnts) claims completion before the MFMA cluster, and the
// counted vmcnt ladder remains the only cross-tile wait, as designed.
//
// LDS swizzle (quarter-wave bank-balanced): 16B k-chunk c of row r stored at
// slot c ^ ((r>>2)&3); slot bits are independent of the row-parity bank bit,
// so every 16-lane quarter of a ds_read_b128 covers all 8 base positions
// with 2 lanes each = the b128 conflict floor (measured: 7.55e7 -> 2.1e6
// conflicts vs the round-1 c^(r&3) variant). Staging pre-swizzles the GLOBAL
// source address ((lane&3)^((lane>>4)&3)); LDS dest stays linear.
//
// Per tile/wave: {4 stage issues | 12 asm ds_read_b128 | lgkmcnt(0) |
// setprio(1) | 16 MFMA | setprio(0) | vmcnt(8)+s_barrier}.
// Assumes M%256==0, N%256==0, K%64==0, K/64 >= 4 (holds: 16384/4096/4096).
// ---------------------------------------------------------------------------
constexpr int BM = 256, BN = 256, BK = 64;

template<int VM>
__device__ __forceinline__ void wait_barrier() {
    if (VM == 8)
        asm volatile("s_waitcnt vmcnt(8)\n\ts_barrier" ::: "memory");
    else if (VM == 4)
        asm volatile("s_waitcnt vmcnt(4)\n\ts_barrier" ::: "memory");
    else if (VM == 0)
        asm volatile("s_waitcnt vmcnt(0)\n\ts_barrier" ::: "memory");
    else
        asm volatile("s_barrier" ::: "memory");
}

template<bool STAGE, int VM>
__device__ __forceinline__ void gemm_tile(
    int t, signed char (*As)[BM * BK], signed char (*Bs)[BN * BK],
    const signed char* aSrc, const signed char* bSrc, int K, int ldsOff,
    int wm, int wn, int r32, int h, v16i (&acc)[4][2])
{
    const int buf = t & 3;

    if (STAGE) {   // issue tile t+3 into buf (t+3)&3 = (t-1)&3 (dead: its
                   // readers all passed the end-of-(t-1) barrier)
        const size_t kt = (size_t)(t + 3) * BK;
        signed char* da = &As[(t + 3) & 3][ldsOff];
        signed char* db = &Bs[(t + 3) & 3][ldsOff];
        load_lds16(aSrc + kt, da);
        load_lds16(aSrc + kt + (size_t)16 * K, da + 1024);
        load_lds16(bSrc + kt, db);
        load_lds16(bSrc + kt + (size_t)16 * K, db + 1024);
    }

    // fragment reads (inline asm): A rows wm*128+mf*32+r32, B rows
    // wn*64+nf*32+r32; global k-chunk g = 2ks+h at slot g ^ ((row>>2)&3);
    // (row>>2)&3 == (r32>>2)&3 since all row bases are multiples of 32.
    const int rs = (r32 >> 2) & 3;
    const uint32_t aBase = lds_addr(&As[buf][0]);
    const uint32_t bBase = lds_addr(&Bs[buf][0]);
    v4i af[2][4], bf[2][2];
#pragma unroll
    for (int ks = 0; ks < 2; ++ks) {
        const int slot = ((2 * ks + h) ^ rs) * 16;
#pragma unroll
        for (int mf = 0; mf < 4; ++mf)
            af[ks][mf] = ds_read_b128_asm(
                aBase + (uint32_t)((wm * 128 + mf * 32 + r32) * BK + slot));
#pragma unroll
        for (int nf = 0; nf < 2; ++nf)
            bf[ks][nf] = ds_read_b128_asm(
                bBase + (uint32_t)((wn * 64 + nf * 32 + r32) * BK + slot));
    }
    asm volatile("s_waitcnt lgkmcnt(0)");
    __builtin_amdgcn_sched_barrier(0);   // MFMAs must not hoist past the wait

    __builtin_amdgcn_s_setprio(1);
#pragma unroll
    for (int ks = 0; ks < 2; ++ks)     // ks outer: 8 independent chains first
#pragma unroll
        for (int mf = 0; mf < 4; ++mf)
#pragma unroll
            for (int nf = 0; nf < 2; ++nf)
                acc[mf][nf] = __builtin_amdgcn_mfma_i32_32x32x32_i8(
                    af[ks][mf], bf[ks][nf], acc[mf][nf], 0, 0, 0);
    __builtin_amdgcn_s_setprio(0);

    // counted wait fused with the barrier: keep tiles t+2,t+3 (8 loads) in
    // flight; the oldest group (tile t+1, read next) is guaranteed landed.
    wait_barrier<VM>();
}

__global__ __launch_bounds__(512, 2) void gemm_i8_kernel(
    const signed char* __restrict__ A, const signed char* __restrict__ B,
    const float* __restrict__ rscale, float* __restrict__ out,
    int M, int N, int K) {
    __shared__ signed char As[4][BM * BK];   // 64 KiB
    __shared__ signed char Bs[4][BN * BK];   // 64 KiB

    const int tid  = threadIdx.x;
    const int wave = tid >> 6;
    const int lane = tid & 63;
    const int wm   = wave >> 2;   // 0..1 : 128-row band
    const int wn   = wave & 3;    // 0..3 : 64-col band
    const int r32  = lane & 31;
    const int h    = lane >> 5;

    // XCD-aware bijective block swizzle (nwg % 8 == 0 here: 16*64 = 1024)
    const int nwg = gridDim.x * gridDim.y;
    int lin = blockIdx.y * gridDim.x + blockIdx.x;
    lin = (lin & 7) * (nwg >> 3) + (lin >> 3);
    const int m0 = (lin / (int)gridDim.x) * BM;
    const int n0 = (lin % (int)gridDim.x) * BN;

    // staging: tile = 16 chunks of 1024B (16 rows x 64B) per operand; wave w
    // owns rows [32w,32w+32) = 2 chunks each of A and B. lane L -> LDS off
    // L*16 = row L>>2, slot L&3; content = global k-chunk (L&3)^((L>>4)&3)
    // (chunks are 16-row aligned so (row>>2)&3 == (L>>4)&3).
    const int lrow = lane >> 2;
    const int lswz = ((lane & 3) ^ ((lane >> 4) & 3)) * 16;
    const signed char* aSrc = A + (size_t)(m0 + wave * 32 + lrow) * K + lswz;
    const signed char* bSrc = B + (size_t)(n0 + wave * 32 + lrow) * K + lswz;
    const int ldsOff = wave * 2048;

    v16i acc[4][2] = {};

    // prologue: stage tiles 0..2 into bufs 0..2 (contiguous 4-load groups)
#pragma unroll
    for (int p = 0; p < 3; ++p) {
        const size_t kt = (size_t)p * BK;
        signed char* da = &As[p][ldsOff];
        signed char* db = &Bs[p][ldsOff];
        load_lds16(aSrc + kt, da);
        load_lds16(aSrc + kt + (size_t)16 * K, da + 1024);
        load_lds16(bSrc + kt, db);
        load_lds16(bSrc + kt + (size_t)16 * K, db + 1024);
    }
    wait_barrier<8>();   // tile 0 landed; tiles 1,2 still in flight

    const int NT = K >> 6;
    int t = 0;
    for (; t < NT - 3; ++t)
        gemm_tile<true, 8>(t, As, Bs, aSrc, bSrc, K, ldsOff, wm, wn, r32, h, acc);
    gemm_tile<false, 4>(NT - 3, As, Bs, aSrc, bSrc, K, ldsOff, wm, wn, r32, h, acc);
    gemm_tile<false, 0>(NT - 2, As, Bs, aSrc, bSrc, K, ldsOff, wm, wn, r32, h, acc);
    gemm_tile<false, -1>(NT - 1, As, Bs, aSrc, bSrc, K, ldsOff, wm, wn, r32, h, acc);

    // epilogue: 32x32 C/D layout: col = lane&31, row = (reg&3)+8*(reg>>2)+4*h
#pragma unroll
    for (int mf = 0; mf < 4; ++mf) {
#pragma unroll
        for (int reg = 0; reg < 16; ++reg) {
            const int m = m0 + wm * 128 + mf * 32 + (reg & 3) + 8 * (reg >> 2) + 4 * h;
            const float rs = rscale[m];
            const size_t rowoff = (size_t)m * N + n0 + wn * 64 + r32;
#pragma unroll
            for (int nf = 0; nf < 2; ++nf)
                out[rowoff + nf * 32] = (float)acc[mf][nf][reg] * rs;
        }
    }
}

// ---------------------------------------------------------------------------
extern "C" void kernel_launch(void* const* d_in, const int* in_sizes, int n_in,
                              void* d_out, int out_size, void* d_ws, size_t ws_size,
                              hipStream_t stream) {
    const float* x  = (const float*)d_in[0];   // [B,S,D] fp32
    const float* nw = (const float*)d_in[1];   // [D]
    const float* w  = (const float*)d_in[2];   // [O,D]
    const int D = in_sizes[1];
    const int M = in_sizes[0] / D;             // B*S tokens
    const int O = in_sizes[2] / D;
    const int WN = O * D;                      // weight element count

    char* ws = (char*)d_ws;
    double* d_sum    = (double*)(ws + 0);
    float*  d_rscale = (float*)(ws + 128);
    size_t off = 128 + (size_t)M * sizeof(float);
    off = (off + 255) & ~(size_t)255;
    signed char* d_wq = (signed char*)(ws + off);
    off += (size_t)WN;
    off = (off + 255) & ~(size_t)255;
    signed char* d_hq = (signed char*)(ws + off);

    hipMemsetAsync(d_sum, 0, sizeof(double), stream);

    wabs_sum_kernel<<<4096, 256, 0, stream>>>((const float4*)w, d_sum, WN / 4);

    wquant_kernel<<<(WN / 4 + 255) / 256, 256, 0, stream>>>(
        (const float4*)w, d_sum, (char4*)d_wq, WN / 4, WN);

    act_quant_kernel<<<M, 256, 0, stream>>>(x, nw, d_sum, WN, d_hq, d_rscale, D);

    dim3 grid(O / 256, M / 256);
    gemm_i8_kernel<<<grid, 512, 0, stream>>>(d_hq, d_wq, d_rscale,
                                             (float*)d_out, M, O, D);
}

// Round 6
// 775.407 us; speedup vs baseline: 1.1149x; 1.0214x over previous
//
#include <hip/hip_runtime.h>
#include <cstdint>
#include <cstddef>

typedef int v4i  __attribute__((ext_vector_type(4)));
typedef int v16i __attribute__((ext_vector_type(16)));

// ---------------------------------------------------------------------------
// async global->LDS 16B copy. LDS dest is wave-uniform base + lane*16.
// ---------------------------------------------------------------------------
__device__ __forceinline__ void load_lds16(const void* g, void* l) {
    __builtin_amdgcn_global_load_lds(
        (const __attribute__((address_space(1))) void*)g,
        (__attribute__((address_space(3))) void*)l,
        16, 0, 0);
}

// 32-bit LDS byte address of a __shared__ object (ptrtoint of AS3 pointer).
__device__ __forceinline__ uint32_t lds_addr(const void* p) {
    return (uint32_t)(uintptr_t)(const __attribute__((address_space(3))) void*)p;
}

// Inline-asm ds_read_b128: opaque to the waitcnt-insertion pass, so the
// compiler cannot attach a conservative "s_waitcnt vmcnt(0)" (drain of
// outstanding global_load_lds) in front of it. Completion is claimed
// manually via counted s_waitcnt lgkmcnt(N) + sched_barrier(0).
__device__ __forceinline__ v4i ds_read_b128_asm(uint32_t addr) {
    v4i r;
    asm volatile("ds_read_b128 %0, %1" : "=v"(r) : "v"(addr));
    return r;
}

// ---------------------------------------------------------------------------
// Kernel 1: sum of |W| (double accumulation; a ternary rounding-boundary flip
// is worth ~0.09 absmax vs threshold 0.105, so keep the mean exact)
// ---------------------------------------------------------------------------
__global__ void wabs_sum_kernel(const float4* __restrict__ w4,
                                double* __restrict__ acc, int n4) {
    double s = 0.0;
    for (int i = blockIdx.x * blockDim.x + threadIdx.x; i < n4;
         i += gridDim.x * blockDim.x) {
        float4 v = w4[i];
        s += (double)fabsf(v.x) + (double)fabsf(v.y) +
             (double)fabsf(v.z) + (double)fabsf(v.w);
    }
    for (int o = 32; o > 0; o >>= 1) s += __shfl_down(s, o);
    __shared__ double sb[4];
    const int wid = threadIdx.x >> 6, lane = threadIdx.x & 63;
    if (lane == 0) sb[wid] = s;
    __syncthreads();
    if (threadIdx.x == 0) atomicAdd(acc, sb[0] + sb[1] + sb[2] + sb[3]);
}

__device__ __forceinline__ float sw_from_sum(const double* sump, int n) {
    float mean = (float)(*sump / (double)n);
    return 1.0f / fmaxf(mean, 1e-5f);   // sw = 1/max(mean|W|, Q_EPS)
}

// ---------------------------------------------------------------------------
// Kernel 2: ternary weight quantization -> int8 {-1,0,1}, row-major [O,K]
// ---------------------------------------------------------------------------
__global__ void wquant_kernel(const float4* __restrict__ w4,
                              const double* __restrict__ sump,
                              char4* __restrict__ wq4, int n4, int n) {
    const float s = sw_from_sum(sump, n);
    int i = blockIdx.x * blockDim.x + threadIdx.x;
    if (i >= n4) return;
    float4 v = w4[i];
    char4 q;
    q.x = (signed char)(int)fmaxf(-1.f, fminf(1.f, rintf(v.x * s)));
    q.y = (signed char)(int)fmaxf(-1.f, fminf(1.f, rintf(v.y * s)));
    q.z = (signed char)(int)fmaxf(-1.f, fminf(1.f, rintf(v.z * s)));
    q.w = (signed char)(int)fmaxf(-1.f, fminf(1.f, rintf(v.w * s)));
    wq4[i] = q;
}

// ---------------------------------------------------------------------------
// Kernel 3: fused RMSNorm + per-token int8 act quant.
// One block per token row (D=4096, 256 thr * 16 elems, kept in registers).
// Also writes rscale[m] = 1/(sx*sw) for the GEMM epilogue.
// ---------------------------------------------------------------------------
__global__ __launch_bounds__(256) void act_quant_kernel(
    const float* __restrict__ x, const float* __restrict__ nw,
    const double* __restrict__ sump, int wcount,
    signed char* __restrict__ hq, float* __restrict__ rscale, int D) {
    const int m = blockIdx.x;
    const int t = threadIdx.x;
    const float4* xr  = (const float4*)(x + (size_t)m * D);
    const float4* nw4 = (const float4*)nw;

    float4 v[4];
    float ss = 0.f;
#pragma unroll
    for (int i = 0; i < 4; ++i) {
        v[i] = xr[t + 256 * i];
        ss += v[i].x * v[i].x + v[i].y * v[i].y +
              v[i].z * v[i].z + v[i].w * v[i].w;
    }
    for (int o = 32; o > 0; o >>= 1) ss += __shfl_down(ss, o);
    __shared__ float sb[4];
    const int wid = t >> 6, lane = t & 63;
    if (lane == 0) sb[wid] = ss;
    __syncthreads();
    const float var  = (sb[0] + sb[1] + sb[2] + sb[3]) / (float)D;
    const float rstd = (float)(1.0 / sqrt((double)var + 1e-5));
    __syncthreads();   // sb re-used below

    float mx = 0.f;
#pragma unroll
    for (int i = 0; i < 4; ++i) {
        float4 g = nw4[t + 256 * i];
        v[i].x = v[i].x * rstd * g.x;
        v[i].y = v[i].y * rstd * g.y;
        v[i].z = v[i].z * rstd * g.z;
        v[i].w = v[i].w * rstd * g.w;
        mx = fmaxf(mx, fmaxf(fmaxf(fabsf(v[i].x), fabsf(v[i].y)),
                             fmaxf(fabsf(v[i].z), fabsf(v[i].w))));
    }
    for (int o = 32; o > 0; o >>= 1) mx = fmaxf(mx, __shfl_down(mx, o));
    if (lane == 0) sb[wid] = mx;
    __syncthreads();
    const float mxa   = fmaxf(fmaxf(sb[0], sb[1]), fmaxf(sb[2], sb[3]));
    const float scale = 127.0f / fmaxf(mxa, 1e-5f);

    char4* hq4 = (char4*)(hq + (size_t)m * D);
#pragma unroll
    for (int i = 0; i < 4; ++i) {
        char4 q;
        q.x = (signed char)(int)fmaxf(-128.f, fminf(127.f, rintf(v[i].x * scale)));
        q.y = (signed char)(int)fmaxf(-128.f, fminf(127.f, rintf(v[i].y * scale)));
        q.z = (signed char)(int)fmaxf(-128.f, fminf(127.f, rintf(v[i].z * scale)));
        q.w = (signed char)(int)fmaxf(-128.f, fminf(127.f, rintf(v[i].w * scale)));
        hq4[t + 256 * i] = q;
    }
    if (t == 0) {
        const float sw = sw_from_sum(sump, wcount);
        rscale[m] = 1.0f / (scale * sw);
    }
}

// ---------------------------------------------------------------------------
// Kernel 4: int8 GEMM  C[m,n] = sum_k A[m,k]*B[n,k]  (both K-contiguous, NT)
//
// Pipelined 256x256 tile, BK=64, 8 waves (2M x 4N), each wave owns 128x64.
// 4-deep LDS K-tile rotation (128 KiB), global_load_lds width-16 staging
// issued 3 tiles ahead, ONE barrier per K-tile with a COUNTED vmcnt
// ("s_waitcnt vmcnt(8); s_barrier" fused asm; ladder 8->4->0 at the tail).
// Fragment reads are inline-asm ds_read_b128 (opaque to the waitcnt pass:
// rounds 3/4 showed this container's compiler inserting vmcnt(0) drains
// before DS-class instructions while global_load_lds is outstanding).
//
// ROUND-6 FIX: counted lgkmcnt phase overlap. Round-5's single lgkmcnt(0)
// before the whole MFMA cluster forced a strict read-phase -> MFMA-phase per
// wave, synchronized CU-wide by the common barrier: LDS-busy (96 b128 =
// ~1156 cyc/tile/CU) and MFMA-busy (~1170 cyc) ran in SERIES (measured 2909
// cyc/tile) instead of overlapped (round-2 compiler-scheduled: 1931).
// Now: issue all 12 reads (ks0 A*4,B*2 then ks1 A*4,B*2), wait lgkmcnt(6)
// (DS retires in order -> exactly ks0's six landed), run 8 ks0 MFMAs while
// the six ks1 reads are in flight, then lgkmcnt(0) + 8 ks1 MFMAs.
// global_load_lds increments vmcnt only, so staging doesn't perturb the
// lgkm count; loop body has no SMEM.
//
// LDS swizzle (quarter-wave bank-balanced): 16B k-chunk c of row r stored at
// slot c ^ ((r>>2)&3); slot bits are independent of the row-parity bank bit,
// so every 16-lane quarter of a ds_read_b128 covers all 8 base positions
// with 2 lanes each = the b128 conflict floor. Staging pre-swizzles the
// GLOBAL source address ((lane&3)^((lane>>4)&3)); LDS dest stays linear.
//
// Per tile/wave: {4 stage issues | 12 asm ds_read_b128 | lgkmcnt(6) |
// 8 MFMA ks0 | lgkmcnt(0) | 8 MFMA ks1 | vmcnt(8)+s_barrier}.
// Assumes M%256==0, N%256==0, K%64==0, K/64 >= 4 (holds: 16384/4096/4096).
// ---------------------------------------------------------------------------
constexpr int BM = 256, BN = 256, BK = 64;

template<int VM>
__device__ __forceinline__ void wait_barrier() {
    if (VM == 8)
        asm volatile("s_waitcnt vmcnt(8)\n\ts_barrier" ::: "memory");
    else if (VM == 4)
        asm volatile("s_waitcnt vmcnt(4)\n\ts_barrier" ::: "memory");
    else if (VM == 0)
        asm volatile("s_waitcnt vmcnt(0)\n\ts_barrier" ::: "memory");
    else
        asm volatile("s_barrier" ::: "memory");
}

template<bool STAGE, int VM>
__device__ __forceinline__ void gemm_tile(
    int t, signed char (*As)[BM * BK], signed char (*Bs)[BN * BK],
    const signed char* aSrc, const signed char* bSrc, int K, int ldsOff,
    int wm, int wn, int r32, int h, v16i (&acc)[4][2])
{
    const int buf = t & 3;

    if (STAGE) {   // issue tile t+3 into buf (t+3)&3 = (t-1)&3 (dead: its
                   // readers all passed the end-of-(t-1) barrier)
        const size_t kt = (size_t)(t + 3) * BK;
        signed char* da = &As[(t + 3) & 3][ldsOff];
        signed char* db = &Bs[(t + 3) & 3][ldsOff];
        load_lds16(aSrc + kt, da);
        load_lds16(aSrc + kt + (size_t)16 * K, da + 1024);
        load_lds16(bSrc + kt, db);
        load_lds16(bSrc + kt + (size_t)16 * K, db + 1024);
    }

    // fragment reads (inline asm): A rows wm*128+mf*32+r32, B rows
    // wn*64+nf*32+r32; global k-chunk g = 2ks+h at slot g ^ ((row>>2)&3);
    // (row>>2)&3 == (r32>>2)&3 since all row bases are multiples of 32.
    const int rs = (r32 >> 2) & 3;
    const uint32_t aBase = lds_addr(&As[buf][0]);
    const uint32_t bBase = lds_addr(&Bs[buf][0]);
    v4i af[2][4], bf[2][2];
#pragma unroll
    for (int ks = 0; ks < 2; ++ks) {
        const int slot = ((2 * ks + h) ^ rs) * 16;
#pragma unroll
        for (int mf = 0; mf < 4; ++mf)
            af[ks][mf] = ds_read_b128_asm(
                aBase + (uint32_t)((wm * 128 + mf * 32 + r32) * BK + slot));
#pragma unroll
        for (int nf = 0; nf < 2; ++nf)
            bf[ks][nf] = ds_read_b128_asm(
                bBase + (uint32_t)((wn * 64 + nf * 32 + r32) * BK + slot));
    }

    // phase 1: ks0 operands landed (first 6 of 12, DS retires in order);
    // ks1's six reads continue in the LDS pipe underneath the ks0 MFMAs.
    asm volatile("s_waitcnt lgkmcnt(6)");
    __builtin_amdgcn_sched_barrier(0);   // MFMAs must not hoist past the wait
    __builtin_amdgcn_s_setprio(1);
#pragma unroll
    for (int mf = 0; mf < 4; ++mf)
#pragma unroll
        for (int nf = 0; nf < 2; ++nf)
            acc[mf][nf] = __builtin_amdgcn_mfma_i32_32x32x32_i8(
                af[0][mf], bf[0][nf], acc[mf][nf], 0, 0, 0);
    __builtin_amdgcn_s_setprio(0);

    // phase 2: ks1 operands landed.
    asm volatile("s_waitcnt lgkmcnt(0)");
    __builtin_amdgcn_sched_barrier(0);
    __builtin_amdgcn_s_setprio(1);
#pragma unroll
    for (int mf = 0; mf < 4; ++mf)
#pragma unroll
        for (int nf = 0; nf < 2; ++nf)
            acc[mf][nf] = __builtin_amdgcn_mfma_i32_32x32x32_i8(
                af[1][mf], bf[1][nf], acc[mf][nf], 0, 0, 0);
    __builtin_amdgcn_s_setprio(0);

    // counted wait fused with the barrier: keep tiles t+2,t+3 (8 loads) in
    // flight; the oldest group (tile t+1, read next) is guaranteed landed.
    wait_barrier<VM>();
}

__global__ __launch_bounds__(512, 2) void gemm_i8_kernel(
    const signed char* __restrict__ A, const signed char* __restrict__ B,
    const float* __restrict__ rscale, float* __restrict__ out,
    int M, int N, int K) {
    __shared__ signed char As[4][BM * BK];   // 64 KiB
    __shared__ signed char Bs[4][BN * BK];   // 64 KiB

    const int tid  = threadIdx.x;
    const int wave = tid >> 6;
    const int lane = tid & 63;
    const int wm   = wave >> 2;   // 0..1 : 128-row band
    const int wn   = wave & 3;    // 0..3 : 64-col band
    const int r32  = lane & 31;
    const int h    = lane >> 5;

    // XCD-aware bijective block swizzle (nwg % 8 == 0 here: 16*64 = 1024)
    const int nwg = gridDim.x * gridDim.y;
    int lin = blockIdx.y * gridDim.x + blockIdx.x;
    lin = (lin & 7) * (nwg >> 3) + (lin >> 3);
    const int m0 = (lin / (int)gridDim.x) * BM;
    const int n0 = (lin % (int)gridDim.x) * BN;

    // staging: tile = 16 chunks of 1024B (16 rows x 64B) per operand; wave w
    // owns rows [32w,32w+32) = 2 chunks each of A and B. lane L -> LDS off
    // L*16 = row L>>2, slot L&3; content = global k-chunk (L&3)^((L>>4)&3)
    // (chunks are 16-row aligned so (row>>2)&3 == (L>>4)&3).
    const int lrow = lane >> 2;
    const int lswz = ((lane & 3) ^ ((lane >> 4) & 3)) * 16;
    const signed char* aSrc = A + (size_t)(m0 + wave * 32 + lrow) * K + lswz;
    const signed char* bSrc = B + (size_t)(n0 + wave * 32 + lrow) * K + lswz;
    const int ldsOff = wave * 2048;

    v16i acc[4][2] = {};

    // prologue: stage tiles 0..2 into bufs 0..2 (contiguous 4-load groups)
#pragma unroll
    for (int p = 0; p < 3; ++p) {
        const size_t kt = (size_t)p * BK;
        signed char* da = &As[p][ldsOff];
        signed char* db = &Bs[p][ldsOff];
        load_lds16(aSrc + kt, da);
        load_lds16(aSrc + kt + (size_t)16 * K, da + 1024);
        load_lds16(bSrc + kt, db);
        load_lds16(bSrc + kt + (size_t)16 * K, db + 1024);
    }
    wait_barrier<8>();   // tile 0 landed; tiles 1,2 still in flight

    const int NT = K >> 6;
    int t = 0;
    for (; t < NT - 3; ++t)
        gemm_tile<true, 8>(t, As, Bs, aSrc, bSrc, K, ldsOff, wm, wn, r32, h, acc);
    gemm_tile<false, 4>(NT - 3, As, Bs, aSrc, bSrc, K, ldsOff, wm, wn, r32, h, acc);
    gemm_tile<false, 0>(NT - 2, As, Bs, aSrc, bSrc, K, ldsOff, wm, wn, r32, h, acc);
    gemm_tile<false, -1>(NT - 1, As, Bs, aSrc, bSrc, K, ldsOff, wm, wn, r32, h, acc);

    // epilogue: 32x32 C/D layout: col = lane&31, row = (reg&3)+8*(reg>>2)+4*h
#pragma unroll
    for (int mf = 0; mf < 4; ++mf) {
#pragma unroll
        for (int reg = 0; reg < 16; ++reg) {
            const int m = m0 + wm * 128 + mf * 32 + (reg & 3) + 8 * (reg >> 2) + 4 * h;
            const float rs = rscale[m];
            const size_t rowoff = (size_t)m * N + n0 + wn * 64 + r32;
#pragma unroll
            for (int nf = 0; nf < 2; ++nf)
                out[rowoff + nf * 32] = (float)acc[mf][nf][reg] * rs;
        }
    }
}

// ---------------------------------------------------------------------------
extern "C" void kernel_launch(void* const* d_in, const int* in_sizes, int n_in,
                              void* d_out, int out_size, void* d_ws, size_t ws_size,
                              hipStream_t stream) {
    const float* x  = (const float*)d_in[0];   // [B,S,D] fp32
    const float* nw = (const float*)d_in[1];   // [D]
    const float* w  = (const float*)d_in[2];   // [O,D]
    const int D = in_sizes[1];
    const int M = in_sizes[0] / D;             // B*S tokens
    const int O = in_sizes[2] / D;
    const int WN = O * D;                      // weight element count

    char* ws = (char*)d_ws;
    double* d_sum    = (double*)(ws + 0);
    float*  d_rscale = (float*)(ws + 128);
    size_t off = 128 + (size_t)M * sizeof(float);
    off = (off + 255) & ~(size_t)255;
    signed char* d_wq = (signed char*)(ws + off);
    off += (size_t)WN;
    off = (off + 255) & ~(size_t)255;
    signed char* d_hq = (signed char*)(ws + off);

    hipMemsetAsync(d_sum, 0, sizeof(double), stream);

    wabs_sum_kernel<<<4096, 256, 0, stream>>>((const float4*)w, d_sum, WN / 4);

    wquant_kernel<<<(WN / 4 + 255) / 256, 256, 0, stream>>>(
        (const float4*)w, d_sum, (char4*)d_wq, WN / 4, WN);

    act_quant_kernel<<<M, 256, 0, stream>>>(x, nw, d_sum, WN, d_hq, d_rscale, D);

    dim3 grid(O / 256, M / 256);
    gemm_i8_kernel<<<grid, 512, 0, stream>>>(d_hq, d_wq, d_rscale,
                                             (float*)d_out, M, O, D);
}